// Round 2
// baseline (305119.556 us; speedup 1.0000x reference)
//
#include <hip/hip_runtime.h>
#include <hip/hip_bf16.h>

#define NEVT 32768
#define NBLK (NEVT / 8)

typedef _Float16 f16;
typedef _Float16 f16x2 __attribute__((ext_vector_type(2)));
typedef float f32x16 __attribute__((ext_vector_type(16)));
typedef float Row128[128];

#ifndef __has_builtin
#define __has_builtin(x) 0
#endif

__device__ __forceinline__ float dot2f(f16x2 a, f16x2 b, float c) {
#if __has_builtin(__builtin_amdgcn_fdot2)
  return __builtin_amdgcn_fdot2(a, b, c, false);
#else
  return c + (float)a[0] * (float)b[0] + (float)a[1] * (float)b[1];
#endif
}

__device__ __forceinline__ float lrelu(float v) { return v >= 0.f ? v : 0.2f * v; }

__device__ __forceinline__ float sigmoidf(float x) {
  return 1.f / (1.f + __expf(-x));
}

__device__ __forceinline__ float tanh_f(float x) {
  float ax = fabsf(x);
  float e = __expf(-2.f * ax);
  float t = (1.f - e) / (1.f + e);
  return x >= 0.f ? t : -t;
}

// One residual block on an 8-row tile held in LDS. 128 threads, thread u owns
// output unit u. Two internal barriers.
__device__ __forceinline__ void res_block(Row128* xb, Row128* hb,
    const float* __restrict__ w1, const float* __restrict__ b1,
    const float* __restrict__ w2, const float* __restrict__ b2, int u) {
  float acc[8];
  float bb = b1[u];
  #pragma unroll
  for (int r = 0; r < 8; ++r) acc[r] = bb;
  #pragma unroll 4
  for (int k = 0; k < 128; ++k) {
    float w = w1[u * 128 + k];
    #pragma unroll
    for (int r = 0; r < 8; ++r) acc[r] += w * xb[r][k];
  }
  #pragma unroll
  for (int r = 0; r < 8; ++r) hb[r][u] = lrelu(acc[r]);
  __syncthreads();
  bb = b2[u];
  #pragma unroll
  for (int r = 0; r < 8; ++r) acc[r] = bb;
  #pragma unroll 4
  for (int k = 0; k < 128; ++k) {
    float w = w2[u * 128 + k];
    #pragma unroll
    for (int r = 0; r < 8; ++r) acc[r] += w * hb[r][k];
  }
  #pragma unroll
  for (int r = 0; r < 8; ++r) xb[r][u] = lrelu(xb[r][u] + acc[r]);
  __syncthreads();
}

// ---------------- Encoder stage 1 ----------------
__global__ __launch_bounds__(128) void enc1_kernel(
    const int* __restrict__ atom, const float* __restrict__ tvec,
    const float* __restrict__ mvec, const float* __restrict__ atom_emb,
    const float* __restrict__ mag_w, const float* __restrict__ mag_b,
    const float* __restrict__ pos_w, const float* __restrict__ pos_b,
    const float* __restrict__ reduce_w, const float* __restrict__ reduce_b,
    const float* __restrict__ net_w1, const float* __restrict__ net_b1,
    const float* __restrict__ net_w2, const float* __restrict__ net_b2,
    const float* __restrict__ final_w, const float* __restrict__ final_b,
    float* __restrict__ xf, float* __restrict__ pg) {
  const int u = threadIdx.x;
  const int r0 = blockIdx.x * 8;
  __shared__ float xin[8][384];
  __shared__ float xb[8][128];
  __shared__ float hb[8][128];
  #pragma unroll
  for (int r = 0; r < 8; ++r) {
    int row = r0 + r;
    xin[r][u] = atom_emb[atom[row] * 128 + u];
    xin[r][128 + u] = tvec[row] * pos_w[u] + pos_b[u];
    xin[r][256 + u] = mvec[row] * mag_w[u] + mag_b[u];
  }
  __syncthreads();
  float acc[8];
  float bb = reduce_b[u];
  #pragma unroll
  for (int r = 0; r < 8; ++r) acc[r] = bb;
  #pragma unroll 4
  for (int k = 0; k < 384; ++k) {
    float w = reduce_w[u * 384 + k];
    #pragma unroll
    for (int r = 0; r < 8; ++r) acc[r] += w * xin[r][k];
  }
  #pragma unroll
  for (int r = 0; r < 8; ++r) xb[r][u] = acc[r];
  __syncthreads();
  for (int blk = 0; blk < 4; ++blk)
    res_block(xb, hb, net_w1 + blk * 16384, net_b1 + blk * 128,
              net_w2 + blk * 16384, net_b2 + blk * 128, u);
  bb = final_b[u];
  #pragma unroll
  for (int r = 0; r < 8; ++r) acc[r] = bb;
  #pragma unroll 4
  for (int k = 0; k < 128; ++k) {
    float w = final_w[u * 128 + k];
    #pragma unroll
    for (int r = 0; r < 8; ++r) acc[r] += w * xb[r][k];
  }
  float s = 0.f;
  #pragma unroll
  for (int r = 0; r < 8; ++r) {
    xf[(r0 + r) * 128 + u] = acc[r];
    s += acc[r];
  }
  pg[blockIdx.x * 128 + u] = s;
}

// ---------------- Deterministic column reduction: sum m rows of [128] -------
__global__ __launch_bounds__(1024) void reduce_kernel(
    const float* __restrict__ src, int m, float* __restrict__ dst) {
  int u = threadIdx.x & 127, c = threadIdx.x >> 7;
  float s = 0.f;
  for (int i = c; i < m; i += 8) s += src[i * 128 + u];
  __shared__ float tmp[8][128];
  tmp[c][u] = s;
  __syncthreads();
  if (c == 0) {
    float t = 0.f;
    #pragma unroll
    for (int j = 0; j < 8; ++j) t += tmp[j][u];
    dst[u] = t;
  }
}

// ---------------- Encoder stage 2 ----------------
__global__ __launch_bounds__(128) void enc2_kernel(
    const float* __restrict__ xf, const float* __restrict__ g,
    const float* __restrict__ redg_w, const float* __restrict__ redg_b,
    const float* __restrict__ wg_w1, const float* __restrict__ wg_b1,
    const float* __restrict__ wg_w2, const float* __restrict__ wg_b2,
    const float* __restrict__ gfinal_w, const float* __restrict__ gfinal_b,
    float* __restrict__ pz) {
  const int u = threadIdx.x;
  const int r0 = blockIdx.x * 8;
  __shared__ float xin[8][256];
  __shared__ float xb[8][128];
  __shared__ float hb[8][128];
  #pragma unroll
  for (int r = 0; r < 8; ++r) {
    xin[r][u] = xf[(r0 + r) * 128 + u];
    xin[r][128 + u] = g[u];
  }
  __syncthreads();
  float acc[8];
  float bb = redg_b[u];
  #pragma unroll
  for (int r = 0; r < 8; ++r) acc[r] = bb;
  #pragma unroll 4
  for (int k = 0; k < 256; ++k) {
    float w = redg_w[u * 256 + k];
    #pragma unroll
    for (int r = 0; r < 8; ++r) acc[r] += w * xin[r][k];
  }
  #pragma unroll
  for (int r = 0; r < 8; ++r) xb[r][u] = acc[r];
  __syncthreads();
  for (int blk = 0; blk < 4; ++blk)
    res_block(xb, hb, wg_w1 + blk * 16384, wg_b1 + blk * 128,
              wg_w2 + blk * 16384, wg_b2 + blk * 128, u);
  bb = gfinal_b[u];
  #pragma unroll
  for (int r = 0; r < 8; ++r) acc[r] = bb;
  #pragma unroll 4
  for (int k = 0; k < 128; ++k) {
    float w = gfinal_w[u * 128 + k];
    #pragma unroll
    for (int r = 0; r < 8; ++r) acc[r] += w * xb[r][k];
  }
  float s = 0.f;
  #pragma unroll
  for (int r = 0; r < 8; ++r) s += acc[r];
  pz[blockIdx.x * 128 + u] = s;
}

// ---------------- Weight pre-conversion f32 -> f16 ----------------
__global__ __launch_bounds__(256) void wprep_kernel(
    const float* __restrict__ wih, const float* __restrict__ whh,
    f16* __restrict__ w16i, f16* __restrict__ w16h) {
  int idx = blockIdx.x * 256 + threadIdx.x;
  if (idx < 196608) {
    w16i[idx] = (f16)wih[idx];
    w16h[idx] = (f16)whh[idx];
  }
}

// ---------------- Sequential GRU decoder (single workgroup, 1024 threads) ---
// R5: HYBRID weight residency. Capacity facts (R4 post-mortem): 1024 thr =
// 4 waves/SIMD -> hard 128-VGPR cap; full residency (192 dw/lane) impossible
// (R4: forced scratch, 2x regression). On-CU capacity: 512 KB regs + 160 KB
// LDS < 768 KB weights -> hybrid:
//   REG  : unit-sets J0,J2,J5  (96 dwords/lane = 384 KB), asm-anchored
//   LDS  : unit-set  J3        (128 KB, lane-contiguous float4 chunks)
//   L2   : unit-sets J1,J4     (256 KB/step streamed, 64 KB per phase)
// Streams are even per phase so the ~575-cyc 64-KB L2 stream overlaps the
// register-fed dot VALU (~450 cyc). Biases moved to LDS tables applied at
// GATE time (frees 6 VGPRs; bhh_n kept separate: it sits inside r*(...)).

#define PW(WV, K) __builtin_bit_cast(f16x2, (WV)[(K)])

#define DGRP(WV, G, Q) \
  a0_ = dot2f(PW(WV, 4*(G)+0), __builtin_bit_cast(f16x2, (Q).x), a0_); \
  a1_ = dot2f(PW(WV, 4*(G)+1), __builtin_bit_cast(f16x2, (Q).y), a1_); \
  a2_ = dot2f(PW(WV, 4*(G)+2), __builtin_bit_cast(f16x2, (Q).z), a2_); \
  a3_ = dot2f(PW(WV, 4*(G)+3), __builtin_bit_cast(f16x2, (Q).w), a3_);

#define DGRPQ(WQ, Q) \
  a0_ = dot2f(__builtin_bit_cast(f16x2, (WQ).x), __builtin_bit_cast(f16x2, (Q).x), a0_); \
  a1_ = dot2f(__builtin_bit_cast(f16x2, (WQ).y), __builtin_bit_cast(f16x2, (Q).y), a1_); \
  a2_ = dot2f(__builtin_bit_cast(f16x2, (WQ).z), __builtin_bit_cast(f16x2, (Q).z), a2_); \
  a3_ = dot2f(__builtin_bit_cast(f16x2, (WQ).w), __builtin_bit_cast(f16x2, (Q).w), a3_);

// Register-resident weights; src staged 16 dwords per half.
#define UNIT_DOT_R(WA, WB, PK) do { \
  int so_ = (PK) & 0xffff, do_ = (PK) >> 16; \
  const float4* s4_ = (const float4*)(srcf + so_); \
  float a0_ = 0.f, a1_ = 0.f, a2_ = 0.f, a3_ = 0.f; \
  float4 q0_ = s4_[0], q1_ = s4_[1], q2_ = s4_[2], q3_ = s4_[3]; \
  DGRP(WA, 0, q0_) DGRP(WA, 1, q1_) DGRP(WA, 2, q2_) DGRP(WA, 3, q3_) \
  __builtin_amdgcn_sched_barrier(0); \
  float4 q4_ = s4_[4], q5_ = s4_[5], q6_ = s4_[6], q7_ = s4_[7]; \
  DGRP(WB, 0, q4_) DGRP(WB, 1, q5_) DGRP(WB, 2, q6_) DGRP(WB, 3, q7_) \
  pgf[do_] = (a0_ + a1_) + (a2_ + a3_); \
} while (0)

// L2-streamed weights (32 dwords) from uniform base w16i + 32-bit offset.
#define UNIT_DOT_S(WOFF, PK) do { \
  int so_ = (PK) & 0xffff, do_ = (PK) >> 16; \
  const float4* wp_ = (const float4*)(w16i + (WOFF)); \
  const float4* s4_ = (const float4*)(srcf + so_); \
  float a0_ = 0.f, a1_ = 0.f, a2_ = 0.f, a3_ = 0.f; \
  { float4 w0_ = wp_[0], w1_ = wp_[1], w2_ = wp_[2], w3_ = wp_[3]; \
    float4 q0_ = s4_[0], q1_ = s4_[1], q2_ = s4_[2], q3_ = s4_[3]; \
    DGRPQ(w0_, q0_) DGRPQ(w1_, q1_) DGRPQ(w2_, q2_) DGRPQ(w3_, q3_) } \
  __builtin_amdgcn_sched_barrier(0); \
  { float4 w0_ = wp_[4], w1_ = wp_[5], w2_ = wp_[6], w3_ = wp_[7]; \
    float4 q0_ = s4_[4], q1_ = s4_[5], q2_ = s4_[6], q3_ = s4_[7]; \
    DGRPQ(w0_, q0_) DGRPQ(w1_, q1_) DGRPQ(w2_, q2_) DGRPQ(w3_, q3_) } \
  pgf[do_] = (a0_ + a1_) + (a2_ + a3_); \
} while (0)

// LDS-resident weights: chunk c of thread t at float4 index (c<<10)+t.
#define UNIT_DOT_L(PK) do { \
  int so_ = (PK) & 0xffff, do_ = (PK) >> 16; \
  const float4* s4_ = (const float4*)(srcf + so_); \
  const float4* wl_ = wlds4s + tid; \
  float a0_ = 0.f, a1_ = 0.f, a2_ = 0.f, a3_ = 0.f; \
  { float4 w0_ = wl_[0<<10], w1_ = wl_[1<<10], w2_ = wl_[2<<10], w3_ = wl_[3<<10]; \
    float4 q0_ = s4_[0], q1_ = s4_[1], q2_ = s4_[2], q3_ = s4_[3]; \
    DGRPQ(w0_, q0_) DGRPQ(w1_, q1_) DGRPQ(w2_, q2_) DGRPQ(w3_, q3_) } \
  __builtin_amdgcn_sched_barrier(0); \
  { float4 w0_ = wl_[4<<10], w1_ = wl_[5<<10], w2_ = wl_[6<<10], w3_ = wl_[7<<10]; \
    float4 q0_ = s4_[4], q1_ = s4_[5], q2_ = s4_[6], q3_ = s4_[7]; \
    DGRPQ(w0_, q0_) DGRPQ(w1_, q1_) DGRPQ(w2_, q2_) DGRPQ(w3_, q3_) } \
  pgf[do_] = (a0_ + a1_) + (a2_ + a3_); \
} while (0)

#define F32T(WV, K, XS, OFF) { f16x2 p_ = PW(WV, (K)); \
  a0_ += (float)p_[0] * (XS)[(OFF) + 2*(K)]; \
  a1_ += (float)p_[1] * (XS)[(OFF) + 2*(K) + 1]; }

#define L4(WV, I, Q) \
  (WV)[4*(I)+0] = (Q).x; (WV)[4*(I)+1] = (Q).y; \
  (WV)[4*(I)+2] = (Q).z; (WV)[4*(I)+3] = (Q).w;

#define LOAD_W16(WA, WB, BASE) do { \
  const float4* p_ = (const float4*)(BASE); \
  float4 q0_ = p_[0], q1_ = p_[1], q2_ = p_[2], q3_ = p_[3]; \
  float4 q4_ = p_[4], q5_ = p_[5], q6_ = p_[6], q7_ = p_[7]; \
  L4(WA, 0, q0_) L4(WA, 1, q1_) L4(WA, 2, q2_) L4(WA, 3, q3_) \
  L4(WB, 0, q4_) L4(WB, 1, q5_) L4(WB, 2, q6_) L4(WB, 3, q7_) \
} while (0)

// srcbuf layout (f16): [0,128) = cur (this layer's input), [128+l*128, ...) = h16[l]
// pg layout (float):   [0,768) = gi partials, [768,1536) = gh partials
// w16h is contiguous at w16i + 196608 (single allocation) -> one 32-bit offset.
#define SETUP_UNIT(J, JJ, P) \
  { int u_ = tid + (JJ)*1024; int lin_ = u_ / 1536; int w_ = u_ % 1536; \
    int layer_ = 2*(P) + lin_; int side_ = w_ / 768; int v_ = w_ % 768; \
    int row_ = v_ >> 1; int half_ = v_ & 1; \
    woff##J = side_ * 196608 + (layer_*384 + row_)*128 + half_*64; \
    pk##J = ((side_ * 768 + v_) << 16) | \
            ((side_ ? (1 + layer_) * 128 : 0) + half_ * 64); }

#define GATE(L, T) \
  if (tid < 128) { \
    const float2* gi2_ = (const float2*)pgf; \
    const float2* gh2_ = (const float2*)(pgf + 768); \
    float2 ar_ = gi2_[tid],      br_ = gh2_[tid]; \
    float2 az_ = gi2_[128+tid],  bz_ = gh2_[128+tid]; \
    float2 an_ = gi2_[256+tid],  bn_ = gh2_[256+tid]; \
    float r_ = sigmoidf((ar_.x + ar_.y) + (br_.x + br_.y) + bsum_r[L][tid]); \
    float z_ = sigmoidf((az_.x + az_.y) + (bz_.x + bz_.y) + bsum_z[L][tid]); \
    float n_ = tanh_f((an_.x + an_.y) + b_in[L][tid] + \
                      r_ * ((bn_.x + bn_.y) + b_hn[L][tid])); \
    float h_ = (1.f - z_) * n_ + z_ * h32[L][tid]; \
    h32[L][tid] = h_; f16 hh_ = (f16)h_; \
    srcbuf[(1 + (L)) * 128 + tid] = hh_; srcbuf[tid] = hh_; \
    if ((L) == 3) enc[(size_t)(T) * 128 + tid] = h_; \
  }

__global__ __attribute__((amdgpu_flat_work_group_size(1024, 1024)))
__attribute__((amdgpu_waves_per_eu(4, 4))) void gru_kernel(
    const f16* __restrict__ w16i, const f16* __restrict__ w16h,
    const float* __restrict__ bih, const float* __restrict__ bhh,
    const float* __restrict__ zvec, float* __restrict__ enc) {
  const int tid = threadIdx.x;

  __shared__ __align__(16) float4 wlds4s[8192];       // 128 KB: J3 weights
  __shared__ __align__(16) float pgbuf[1536];         // 6 KB
  __shared__ __align__(16) f16 srcbuf[640];           // 1.25 KB
  __shared__ __align__(16) float h32[4][128];         // 2 KB
  __shared__ __align__(16) float cur32[128];          // 0.5 KB
  __shared__ float bsum_r[4][128], bsum_z[4][128];    // 4 KB
  __shared__ float b_in[4][128], b_hn[4][128];        // 4 KB

  float* const pgf = pgbuf;
  const f16* const srcf = srcbuf;

  int woff0, pk0; int woff1, pk1; int woff2, pk2;
  int woff3, pk3; int woff4, pk4; int woff5, pk5;

  SETUP_UNIT(0, 0, 0) SETUP_UNIT(1, 1, 0) SETUP_UNIT(2, 2, 0)
  SETUP_UNIT(3, 0, 1) SETUP_UNIT(4, 1, 1) SETUP_UNIT(5, 2, 1)

  // Register-resident sets J0, J2, J5 (96 VGPRs/lane).
  f32x16 w0a, w0b, w2a, w2b, w5a, w5b;
  LOAD_W16(w0a, w0b, w16i + woff0);
  LOAD_W16(w2a, w2b, w16i + woff2);
  LOAD_W16(w5a, w5b, w16i + woff5);
  asm volatile("" : "+v"(w0a), "+v"(w0b), "+v"(w2a), "+v"(w2b),
                    "+v"(w5a), "+v"(w5b));

  // LDS-resident set J3: chunk c of thread t at float4 index (c<<10)+t.
  {
    const float4* wsrc_ = (const float4*)(w16i + woff3);
    #pragma unroll
    for (int c = 0; c < 8; ++c) wlds4s[(c << 10) + tid] = wsrc_[c];
  }

  if (tid < 128) {
    cur32[tid] = zvec[tid];
    srcbuf[tid] = (f16)0.f;
    #pragma unroll
    for (int l = 0; l < 4; ++l) {
      h32[l][tid] = 0.f;
      srcbuf[(1 + l) * 128 + tid] = (f16)0.f;
    }
  }
  if (tid < 512) {
    int l_ = tid >> 7, row_ = tid & 127;
    bsum_r[l_][row_] = bih[l_*384 + row_]       + bhh[l_*384 + row_];
    bsum_z[l_][row_] = bih[l_*384 + 128 + row_] + bhh[l_*384 + 128 + row_];
    b_in[l_][row_]   = bih[l_*384 + 256 + row_];
    b_hn[l_][row_]   = bhh[l_*384 + 256 + row_];
  }
  __syncthreads();

  // ---- peeled step t = 0 (layer-0 gi from f32 z; h == 0 elsewhere) ----
  // z ~1e7 overflows f16 -> f32 path against the resident w0a/w0b.
  {
    if (tid < 768) {
      int so_ = pk0 & 0xffff, do_ = pk0 >> 16;
      const float* xs_ = cur32 + so_;
      float a0_ = 0.f, a1_ = 0.f;
      F32T(w0a,0,xs_,0) F32T(w0a,1,xs_,0) F32T(w0a,2,xs_,0) F32T(w0a,3,xs_,0)
      F32T(w0a,4,xs_,0) F32T(w0a,5,xs_,0) F32T(w0a,6,xs_,0) F32T(w0a,7,xs_,0)
      F32T(w0a,8,xs_,0) F32T(w0a,9,xs_,0) F32T(w0a,10,xs_,0) F32T(w0a,11,xs_,0)
      F32T(w0a,12,xs_,0) F32T(w0a,13,xs_,0) F32T(w0a,14,xs_,0) F32T(w0a,15,xs_,0)
      F32T(w0b,0,xs_,32) F32T(w0b,1,xs_,32) F32T(w0b,2,xs_,32) F32T(w0b,3,xs_,32)
      F32T(w0b,4,xs_,32) F32T(w0b,5,xs_,32) F32T(w0b,6,xs_,32) F32T(w0b,7,xs_,32)
      F32T(w0b,8,xs_,32) F32T(w0b,9,xs_,32) F32T(w0b,10,xs_,32) F32T(w0b,11,xs_,32)
      F32T(w0b,12,xs_,32) F32T(w0b,13,xs_,32) F32T(w0b,14,xs_,32) F32T(w0b,15,xs_,32)
      pgf[do_] = a0_ + a1_;
    } else {
      UNIT_DOT_R(w0a, w0b, pk0);
    }
    if (tid < 512) UNIT_DOT_S(woff1, pk1);
    __syncthreads();
    GATE(0, 0)
    __syncthreads();
    if (tid >= 512) UNIT_DOT_S(woff1, pk1);
    UNIT_DOT_R(w2a, w2b, pk2);
    __syncthreads();
    GATE(1, 0)
    __syncthreads();
    UNIT_DOT_L(pk3);
    if (tid < 512) UNIT_DOT_S(woff4, pk4);
    __syncthreads();
    GATE(2, 0)
    __syncthreads();
    if (tid >= 512) UNIT_DOT_S(woff4, pk4);
    UNIT_DOT_R(w5a, w5b, pk5);
    __syncthreads();
    GATE(3, 0)
    __syncthreads();
  }

  for (int t = 1; t < NEVT; ++t) {
    // ---- phase 0 (layer 0): J1-half streamed, J0 register ----
    if (tid < 512) UNIT_DOT_S(woff1, pk1);
    UNIT_DOT_R(w0a, w0b, pk0);
    __syncthreads();
    GATE(0, t)
    __syncthreads();
    // ---- phase 1 (layer 1): J1-half streamed, J2 register ----
    if (tid >= 512) UNIT_DOT_S(woff1, pk1);
    UNIT_DOT_R(w2a, w2b, pk2);
    __syncthreads();
    GATE(1, t)
    __syncthreads();
    // ---- phase 2 (layer 2): J4-half streamed, J3 LDS ----
    if (tid < 512) UNIT_DOT_S(woff4, pk4);
    UNIT_DOT_L(pk3);
    __syncthreads();
    GATE(2, t)
    __syncthreads();
    // ---- phase 3 (layer 3): J4-half streamed, J5 register ----
    if (tid >= 512) UNIT_DOT_S(woff4, pk4);
    UNIT_DOT_R(w5a, w5b, pk5);
    __syncthreads();
    GATE(3, t)
    __syncthreads();
  }
}

// ---------------- Output heads ----------------
__global__ __launch_bounds__(128) void heads_kernel(
    const float* __restrict__ enc,
    const float* __restrict__ ah_w1, const float* __restrict__ ah_b1,
    const float* __restrict__ ah_w2, const float* __restrict__ ah_b2,
    const float* __restrict__ ah_w, const float* __restrict__ ah_b,
    const float* __restrict__ ph_w1, const float* __restrict__ ph_b1,
    const float* __restrict__ ph_w2, const float* __restrict__ ph_b2,
    const float* __restrict__ ph_w, const float* __restrict__ ph_b,
    const float* __restrict__ mh_w1, const float* __restrict__ mh_b1,
    const float* __restrict__ mh_w2, const float* __restrict__ mh_b2,
    const float* __restrict__ mh_w, const float* __restrict__ mh_b,
    float* __restrict__ oa, float* __restrict__ op, float* __restrict__ om) {
  const int u = threadIdx.x;
  const int r0 = blockIdx.x * 8;
  __shared__ float eb[8][128], xb[8][128], hb[8][128];
  #pragma unroll
  for (int r = 0; r < 8; ++r) eb[r][u] = enc[(size_t)(r0 + r) * 128 + u];
  // ---- atoms head ----
  #pragma unroll
  for (int r = 0; r < 8; ++r) xb[r][u] = eb[r][u];
  __syncthreads();
  for (int blk = 0; blk < 2; ++blk)
    res_block(xb, hb, ah_w1 + blk * 16384, ah_b1 + blk * 128,
              ah_w2 + blk * 16384, ah_b2 + blk * 128, u);
  {
    float acc[8];
    float bb = ah_b[u];
    #pragma unroll
    for (int r = 0; r < 8; ++r) acc[r] = bb;
    #pragma unroll 4
    for (int k = 0; k < 128; ++k) {
      float w = ah_w[u * 128 + k];
      #pragma unroll
      for (int r = 0; r < 8; ++r) acc[r] += w * xb[r][k];
    }
    #pragma unroll
    for (int r = 0; r < 8; ++r) oa[(size_t)(r0 + r) * 128 + u] = acc[r];
  }
  __syncthreads();
  // ---- pos head ----
  #pragma unroll
  for (int r = 0; r < 8; ++r) xb[r][u] = eb[r][u];
  __syncthreads();
  for (int blk = 0; blk < 2; ++blk)
    res_block(xb, hb, ph_w1 + blk * 16384, ph_b1 + blk * 128,
              ph_w2 + blk * 16384, ph_b2 + blk * 128, u);
  if (u < 8) {
    int r = u;
    float s = ph_b[0];
    for (int k = 0; k < 128; ++k) s += ph_w[k] * xb[r][k];
    s = s < 0.f ? 0.f : (s > 1.f ? 1.f : s);
    op[r0 + r] = s;
  }
  __syncthreads();
  // ---- mags head ----
  #pragma unroll
  for (int r = 0; r < 8; ++r) xb[r][u] = eb[r][u];
  __syncthreads();
  for (int blk = 0; blk < 2; ++blk)
    res_block(xb, hb, mh_w1 + blk * 16384, mh_b1 + blk * 128,
              mh_w2 + blk * 16384, mh_b2 + blk * 128, u);
  if (u < 8) {
    int r = u;
    float s = mh_b[0];
    for (int k = 0; k < 128; ++k) s += mh_w[k] * xb[r][k];
    om[r0 + r] = s;
  }
}

extern "C" void kernel_launch(void* const* d_in, const int* in_sizes, int n_in,
                              void* d_out, int out_size, void* d_ws, size_t ws_size,
                              hipStream_t stream) {
  const int* atom = (const int*)d_in[0];
  const float* tvec = (const float*)d_in[1];
  const float* mvec = (const float*)d_in[2];
  const float* atom_emb = (const float*)d_in[3];
  const float* mag_w = (const float*)d_in[4];
  const float* mag_b = (const float*)d_in[5];
  const float* pos_w = (const float*)d_in[6];
  const float* pos_b = (const float*)d_in[7];
  const float* reduce_w = (const float*)d_in[8];
  const float* reduce_b = (const float*)d_in[9];
  const float* net_w1 = (const float*)d_in[10];
  const float* net_b1 = (const float*)d_in[11];
  const float* net_w2 = (const float*)d_in[12];
  const float* net_b2 = (const float*)d_in[13];
  const float* final_w = (const float*)d_in[14];
  const float* final_b = (const float*)d_in[15];
  const float* redg_w = (const float*)d_in[16];
  const float* redg_b = (const float*)d_in[17];
  const float* wg_w1 = (const float*)d_in[18];
  const float* wg_b1 = (const float*)d_in[19];
  const float* wg_w2 = (const float*)d_in[20];
  const float* wg_b2 = (const float*)d_in[21];
  const float* gfinal_w = (const float*)d_in[22];
  const float* gfinal_b = (const float*)d_in[23];
  const float* gru_wih = (const float*)d_in[24];
  const float* gru_whh = (const float*)d_in[25];
  const float* gru_bih = (const float*)d_in[26];
  const float* gru_bhh = (const float*)d_in[27];
  const float* ah_w1 = (const float*)d_in[28];
  const float* ah_b1 = (const float*)d_in[29];
  const float* ah_w2 = (const float*)d_in[30];
  const float* ah_b2 = (const float*)d_in[31];
  const float* ah_w = (const float*)d_in[32];
  const float* ah_b = (const float*)d_in[33];
  const float* ph_w1 = (const float*)d_in[34];
  const float* ph_b1 = (const float*)d_in[35];
  const float* ph_w2 = (const float*)d_in[36];
  const float* ph_b2 = (const float*)d_in[37];
  const float* ph_w = (const float*)d_in[38];
  const float* ph_b = (const float*)d_in[39];
  const float* mh_w1 = (const float*)d_in[40];
  const float* mh_b1 = (const float*)d_in[41];
  const float* mh_w2 = (const float*)d_in[42];
  const float* mh_b2 = (const float*)d_in[43];
  const float* mh_w = (const float*)d_in[44];
  const float* mh_b = (const float*)d_in[45];

  float* out = (float*)d_out;
  float* oa = out;                        // atoms [N,128]
  float* op = out + (size_t)NEVT * 128;   // pos [N]
  float* om = op + NEVT;                  // mags [N]
  float* oz = om + NEVT;                  // z [128]

  float* enc = (float*)d_ws;              // encodings [N,128] : 16 MB
  float* pg = enc + (size_t)NEVT * 128;   // stage-1 partials: 2 MB (reused for w16)
  float* pz = pg + (size_t)NBLK * 128;    // stage-2 partials: 2 MB
  float* gv = pz + (size_t)NBLK * 128;    // g [128]
  float* xf = oa;  // stage-1 output staged in atoms region; heads overwrite later

  // f16 weight copies overlay the pg region once pg has been reduced into gv.
  f16* w16i = (f16*)pg;                   // 384 KB
  f16* w16h = w16i + 196608;              // 384 KB (contiguous with w16i)

  enc1_kernel<<<NBLK, 128, 0, stream>>>(atom, tvec, mvec, atom_emb, mag_w, mag_b,
      pos_w, pos_b, reduce_w, reduce_b, net_w1, net_b1, net_w2, net_b2,
      final_w, final_b, xf, pg);
  reduce_kernel<<<1, 1024, 0, stream>>>(pg, NBLK, gv);
  wprep_kernel<<<768, 256, 0, stream>>>(gru_wih, gru_whh, w16i, w16h);
  enc2_kernel<<<NBLK, 128, 0, stream>>>(xf, gv, redg_w, redg_b, wg_w1, wg_b1,
      wg_w2, wg_b2, gfinal_w, gfinal_b, pz);
  reduce_kernel<<<1, 1024, 0, stream>>>(pz, NBLK, oz);
  gru_kernel<<<1, 1024, 0, stream>>>(w16i, w16h, gru_bih, gru_bhh, oz, enc);
  heads_kernel<<<NBLK, 128, 0, stream>>>(enc, ah_w1, ah_b1, ah_w2, ah_b2, ah_w, ah_b,
      ph_w1, ph_b1, ph_w2, ph_b2, ph_w, ph_b, mh_w1, mh_b1, mh_w2, mh_b2, mh_w, mh_b,
      oa, op, om);
}

// Round 3
// 108634.253 us; speedup vs baseline: 2.8087x; 2.8087x over previous
//
#include <hip/hip_runtime.h>
#include <hip/hip_bf16.h>

#define NEVT 32768
#define NBLK (NEVT / 8)

typedef _Float16 f16;
typedef _Float16 f16x2 __attribute__((ext_vector_type(2)));
typedef float f32x16 __attribute__((ext_vector_type(16)));
typedef float Row128[128];

#ifndef __has_builtin
#define __has_builtin(x) 0
#endif

__device__ __forceinline__ float dot2f(f16x2 a, f16x2 b, float c) {
#if __has_builtin(__builtin_amdgcn_fdot2)
  return __builtin_amdgcn_fdot2(a, b, c, false);
#else
  return c + (float)a[0] * (float)b[0] + (float)a[1] * (float)b[1];
#endif
}

__device__ __forceinline__ float lrelu(float v) { return v >= 0.f ? v : 0.2f * v; }

__device__ __forceinline__ float sigmoidf(float x) {
  return 1.f / (1.f + __expf(-x));
}

__device__ __forceinline__ float tanh_f(float x) {
  float ax = fabsf(x);
  float e = __expf(-2.f * ax);
  float t = (1.f - e) / (1.f + e);
  return x >= 0.f ? t : -t;
}

// One residual block on an 8-row tile held in LDS. 128 threads, thread u owns
// output unit u. Two internal barriers.
__device__ __forceinline__ void res_block(Row128* xb, Row128* hb,
    const float* __restrict__ w1, const float* __restrict__ b1,
    const float* __restrict__ w2, const float* __restrict__ b2, int u) {
  float acc[8];
  float bb = b1[u];
  #pragma unroll
  for (int r = 0; r < 8; ++r) acc[r] = bb;
  #pragma unroll 4
  for (int k = 0; k < 128; ++k) {
    float w = w1[u * 128 + k];
    #pragma unroll
    for (int r = 0; r < 8; ++r) acc[r] += w * xb[r][k];
  }
  #pragma unroll
  for (int r = 0; r < 8; ++r) hb[r][u] = lrelu(acc[r]);
  __syncthreads();
  bb = b2[u];
  #pragma unroll
  for (int r = 0; r < 8; ++r) acc[r] = bb;
  #pragma unroll 4
  for (int k = 0; k < 128; ++k) {
    float w = w2[u * 128 + k];
    #pragma unroll
    for (int r = 0; r < 8; ++r) acc[r] += w * hb[r][k];
  }
  #pragma unroll
  for (int r = 0; r < 8; ++r) xb[r][u] = lrelu(xb[r][u] + acc[r]);
  __syncthreads();
}

// ---------------- Encoder stage 1 ----------------
__global__ __launch_bounds__(128) void enc1_kernel(
    const int* __restrict__ atom, const float* __restrict__ tvec,
    const float* __restrict__ mvec, const float* __restrict__ atom_emb,
    const float* __restrict__ mag_w, const float* __restrict__ mag_b,
    const float* __restrict__ pos_w, const float* __restrict__ pos_b,
    const float* __restrict__ reduce_w, const float* __restrict__ reduce_b,
    const float* __restrict__ net_w1, const float* __restrict__ net_b1,
    const float* __restrict__ net_w2, const float* __restrict__ net_b2,
    const float* __restrict__ final_w, const float* __restrict__ final_b,
    float* __restrict__ xf, float* __restrict__ pg) {
  const int u = threadIdx.x;
  const int r0 = blockIdx.x * 8;
  __shared__ float xin[8][384];
  __shared__ float xb[8][128];
  __shared__ float hb[8][128];
  #pragma unroll
  for (int r = 0; r < 8; ++r) {
    int row = r0 + r;
    xin[r][u] = atom_emb[atom[row] * 128 + u];
    xin[r][128 + u] = tvec[row] * pos_w[u] + pos_b[u];
    xin[r][256 + u] = mvec[row] * mag_w[u] + mag_b[u];
  }
  __syncthreads();
  float acc[8];
  float bb = reduce_b[u];
  #pragma unroll
  for (int r = 0; r < 8; ++r) acc[r] = bb;
  #pragma unroll 4
  for (int k = 0; k < 384; ++k) {
    float w = reduce_w[u * 384 + k];
    #pragma unroll
    for (int r = 0; r < 8; ++r) acc[r] += w * xin[r][k];
  }
  #pragma unroll
  for (int r = 0; r < 8; ++r) xb[r][u] = acc[r];
  __syncthreads();
  for (int blk = 0; blk < 4; ++blk)
    res_block(xb, hb, net_w1 + blk * 16384, net_b1 + blk * 128,
              net_w2 + blk * 16384, net_b2 + blk * 128, u);
  bb = final_b[u];
  #pragma unroll
  for (int r = 0; r < 8; ++r) acc[r] = bb;
  #pragma unroll 4
  for (int k = 0; k < 128; ++k) {
    float w = final_w[u * 128 + k];
    #pragma unroll
    for (int r = 0; r < 8; ++r) acc[r] += w * xb[r][k];
  }
  float s = 0.f;
  #pragma unroll
  for (int r = 0; r < 8; ++r) {
    xf[(r0 + r) * 128 + u] = acc[r];
    s += acc[r];
  }
  pg[blockIdx.x * 128 + u] = s;
}

// ---------------- Deterministic column reduction: sum m rows of [128] -------
__global__ __launch_bounds__(1024) void reduce_kernel(
    const float* __restrict__ src, int m, float* __restrict__ dst) {
  int u = threadIdx.x & 127, c = threadIdx.x >> 7;
  float s = 0.f;
  for (int i = c; i < m; i += 8) s += src[i * 128 + u];
  __shared__ float tmp[8][128];
  tmp[c][u] = s;
  __syncthreads();
  if (c == 0) {
    float t = 0.f;
    #pragma unroll
    for (int j = 0; j < 8; ++j) t += tmp[j][u];
    dst[u] = t;
  }
}

// ---------------- Encoder stage 2 ----------------
__global__ __launch_bounds__(128) void enc2_kernel(
    const float* __restrict__ xf, const float* __restrict__ g,
    const float* __restrict__ redg_w, const float* __restrict__ redg_b,
    const float* __restrict__ wg_w1, const float* __restrict__ wg_b1,
    const float* __restrict__ wg_w2, const float* __restrict__ wg_b2,
    const float* __restrict__ gfinal_w, const float* __restrict__ gfinal_b,
    float* __restrict__ pz) {
  const int u = threadIdx.x;
  const int r0 = blockIdx.x * 8;
  __shared__ float xin[8][256];
  __shared__ float xb[8][128];
  __shared__ float hb[8][128];
  #pragma unroll
  for (int r = 0; r < 8; ++r) {
    xin[r][u] = xf[(r0 + r) * 128 + u];
    xin[r][128 + u] = g[u];
  }
  __syncthreads();
  float acc[8];
  float bb = redg_b[u];
  #pragma unroll
  for (int r = 0; r < 8; ++r) acc[r] = bb;
  #pragma unroll 4
  for (int k = 0; k < 256; ++k) {
    float w = redg_w[u * 256 + k];
    #pragma unroll
    for (int r = 0; r < 8; ++r) acc[r] += w * xin[r][k];
  }
  #pragma unroll
  for (int r = 0; r < 8; ++r) xb[r][u] = acc[r];
  __syncthreads();
  for (int blk = 0; blk < 4; ++blk)
    res_block(xb, hb, wg_w1 + blk * 16384, wg_b1 + blk * 128,
              wg_w2 + blk * 16384, wg_b2 + blk * 128, u);
  bb = gfinal_b[u];
  #pragma unroll
  for (int r = 0; r < 8; ++r) acc[r] = bb;
  #pragma unroll 4
  for (int k = 0; k < 128; ++k) {
    float w = gfinal_w[u * 128 + k];
    #pragma unroll
    for (int r = 0; r < 8; ++r) acc[r] += w * xb[r][k];
  }
  float s = 0.f;
  #pragma unroll
  for (int r = 0; r < 8; ++r) s += acc[r];
  pz[blockIdx.x * 128 + u] = s;
}

// ---------------- Weight pre-conversion f32 -> f16 ----------------
__global__ __launch_bounds__(256) void wprep_kernel(
    const float* __restrict__ wih, const float* __restrict__ whh,
    f16* __restrict__ w16i, f16* __restrict__ w16h) {
  int idx = blockIdx.x * 256 + threadIdx.x;
  if (idx < 196608) {
    w16i[idx] = (f16)wih[idx];
    w16h[idx] = (f16)whh[idx];
  }
}

// ---------------- Sequential GRU decoder (single workgroup, 512 threads) ----
// R6: fix the budget, not the allocator. R4/R5 post-mortem: 1024 threads =
// 4 waves/SIMD = hard 128-VGPR cap; any anchored residency > ~80 dw spills to
// scratch (VGPR_Count 52/64, catastrophic serialization). VALU throughput is
// per-CU, not per-thread, so 512 threads (8 waves, 2/SIMD) gives the SAME
// compute rate with a 256-VGPR/lane budget.
// Unit mapping (row-grouped): per phase (layer l), thread owns 3 consecutive
// rows of ONE (side, half): side = tid>>8 (0=gi,1=gh), half = ti&1,
// rows rb..rb+2 (rb = 3*(ti>>1)). One 128-B src slice per thread per phase,
// read once from LDS, reused by 3 accumulators (3x less LDS broadcast traffic
// than the old mapping, and no divergent phase splits).
// Residency per thread (12 row-units x 32 dw = 384 dw total):
//   REG  (anchored, 192 dw): A-rows (rb) layers 0-3 + B-rows (rb+1) layers 0,1
//   LDS  (128 KB)          : B-rows layers 2,3 (lane-contiguous float4)
//   L2   (64 KB/phase)     : C-rows (rb+2), coalesced 256-B blocks
// Peak live ~230 < 256. Peeled t=0 runs layer-0 gi in f32 (z ~1e7 overflows
// f16) against the anchored regs + a one-time global f32 path for the C row.

#define PW(WV, K) __builtin_bit_cast(f16x2, (WV)[(K)])

#define D4(WV, B, Q, A) \
  A = dot2f(PW(WV,(B)+0), __builtin_bit_cast(f16x2,(Q).x), A); \
  A = dot2f(PW(WV,(B)+1), __builtin_bit_cast(f16x2,(Q).y), A); \
  A = dot2f(PW(WV,(B)+2), __builtin_bit_cast(f16x2,(Q).z), A); \
  A = dot2f(PW(WV,(B)+3), __builtin_bit_cast(f16x2,(Q).w), A);

#define D4Q(WQ, Q, A) \
  A = dot2f(__builtin_bit_cast(f16x2,(WQ).x), __builtin_bit_cast(f16x2,(Q).x), A); \
  A = dot2f(__builtin_bit_cast(f16x2,(WQ).y), __builtin_bit_cast(f16x2,(Q).y), A); \
  A = dot2f(__builtin_bit_cast(f16x2,(WQ).z), __builtin_bit_cast(f16x2,(Q).z), A); \
  A = dot2f(__builtin_bit_cast(f16x2,(WQ).w), __builtin_bit_cast(f16x2,(Q).w), A);

#define F32T(WV, K, XS, OFF) { f16x2 p_ = PW(WV, (K)); \
  a0_ += (float)p_[0] * (XS)[(OFF) + 2*(K)]; \
  a1_ += (float)p_[1] * (XS)[(OFF) + 2*(K) + 1]; }

#define F32T16(WV, XS, OFF) \
  F32T(WV,0,XS,OFF) F32T(WV,1,XS,OFF) F32T(WV,2,XS,OFF) F32T(WV,3,XS,OFF) \
  F32T(WV,4,XS,OFF) F32T(WV,5,XS,OFF) F32T(WV,6,XS,OFF) F32T(WV,7,XS,OFF) \
  F32T(WV,8,XS,OFF) F32T(WV,9,XS,OFF) F32T(WV,10,XS,OFF) F32T(WV,11,XS,OFF) \
  F32T(WV,12,XS,OFF) F32T(WV,13,XS,OFF) F32T(WV,14,XS,OFF) F32T(WV,15,XS,OFF)

#define L4(WV, I, Q) \
  (WV)[4*(I)+0] = (Q).x; (WV)[4*(I)+1] = (Q).y; \
  (WV)[4*(I)+2] = (Q).z; (WV)[4*(I)+3] = (Q).w;

#define LOAD_W16(WA, WB, BASE) do { \
  const float4* p_ = (const float4*)(BASE); \
  float4 q0_ = p_[0], q1_ = p_[1], q2_ = p_[2], q3_ = p_[3]; \
  float4 q4_ = p_[4], q5_ = p_[5], q6_ = p_[6], q7_ = p_[7]; \
  L4(WA, 0, q0_) L4(WA, 1, q1_) L4(WA, 2, q2_) L4(WA, 3, q3_) \
  L4(WB, 0, q4_) L4(WB, 1, q5_) L4(WB, 2, q6_) L4(WB, 3, q7_) \
} while (0)

// Phase header/tail. srcbuf (f16): [0,128)=cur, [128+l*128,...)=h16[l].
// pg (float): [0,768)=gi partials (row*2+half), [768,1536)=gh.
#define PH_HEAD(L) \
  const float4* s4_ = (const float4*)(srcf + soff_base + (L) * sideOff); \
  const float4* wc4_ = (const float4*)(w16 + (wCb + (L) * 49152)); \
  float aA0_=0.f,aA1_=0.f,aB0_=0.f,aB1_=0.f,aC0_=0.f,aC1_=0.f; \
  float4 q0_, q1_, wq0_, wq1_;

#define PH_TAIL() \
  pgf[d0] = aA0_ + aA1_; pgf[d0+2] = aB0_ + aB1_; pgf[d0+4] = aC0_ + aC1_;

// B-rows from registers (layers 0,1)
#define PH_R(L, Aa, Ab, Ba, Bb) do { PH_HEAD(L) \
  q0_=s4_[0]; q1_=s4_[1]; wq0_=wc4_[0]; wq1_=wc4_[1]; \
  D4(Aa,0,q0_,aA0_) D4(Aa,4,q1_,aA1_) D4(Ba,0,q0_,aB0_) D4(Ba,4,q1_,aB1_) \
  D4Q(wq0_,q0_,aC0_) D4Q(wq1_,q1_,aC1_) \
  q0_=s4_[2]; q1_=s4_[3]; wq0_=wc4_[2]; wq1_=wc4_[3]; \
  D4(Aa,8,q0_,aA0_) D4(Aa,12,q1_,aA1_) D4(Ba,8,q0_,aB0_) D4(Ba,12,q1_,aB1_) \
  D4Q(wq0_,q0_,aC0_) D4Q(wq1_,q1_,aC1_) \
  q0_=s4_[4]; q1_=s4_[5]; wq0_=wc4_[4]; wq1_=wc4_[5]; \
  D4(Ab,0,q0_,aA0_) D4(Ab,4,q1_,aA1_) D4(Bb,0,q0_,aB0_) D4(Bb,4,q1_,aB1_) \
  D4Q(wq0_,q0_,aC0_) D4Q(wq1_,q1_,aC1_) \
  q0_=s4_[6]; q1_=s4_[7]; wq0_=wc4_[6]; wq1_=wc4_[7]; \
  D4(Ab,8,q0_,aA0_) D4(Ab,12,q1_,aA1_) D4(Bb,8,q0_,aB0_) D4(Bb,12,q1_,aB1_) \
  D4Q(wq0_,q0_,aC0_) D4Q(wq1_,q1_,aC1_) \
  PH_TAIL() } while (0)

// B-rows from LDS (layers 2,3); WL = wldsB2 / wldsB3, float4 idx c*512+tid
#define PH_L(L, Aa, Ab, WL) do { PH_HEAD(L) \
  float4 bw0_, bw1_; \
  q0_=s4_[0]; q1_=s4_[1]; wq0_=wc4_[0]; wq1_=wc4_[1]; \
  bw0_=(WL)[0*512+tid]; bw1_=(WL)[1*512+tid]; \
  D4(Aa,0,q0_,aA0_) D4(Aa,4,q1_,aA1_) D4Q(bw0_,q0_,aB0_) D4Q(bw1_,q1_,aB1_) \
  D4Q(wq0_,q0_,aC0_) D4Q(wq1_,q1_,aC1_) \
  q0_=s4_[2]; q1_=s4_[3]; wq0_=wc4_[2]; wq1_=wc4_[3]; \
  bw0_=(WL)[2*512+tid]; bw1_=(WL)[3*512+tid]; \
  D4(Aa,8,q0_,aA0_) D4(Aa,12,q1_,aA1_) D4Q(bw0_,q0_,aB0_) D4Q(bw1_,q1_,aB1_) \
  D4Q(wq0_,q0_,aC0_) D4Q(wq1_,q1_,aC1_) \
  q0_=s4_[4]; q1_=s4_[5]; wq0_=wc4_[4]; wq1_=wc4_[5]; \
  bw0_=(WL)[4*512+tid]; bw1_=(WL)[5*512+tid]; \
  D4(Ab,0,q0_,aA0_) D4(Ab,4,q1_,aA1_) D4Q(bw0_,q0_,aB0_) D4Q(bw1_,q1_,aB1_) \
  D4Q(wq0_,q0_,aC0_) D4Q(wq1_,q1_,aC1_) \
  q0_=s4_[6]; q1_=s4_[7]; wq0_=wc4_[6]; wq1_=wc4_[7]; \
  bw0_=(WL)[6*512+tid]; bw1_=(WL)[7*512+tid]; \
  D4(Ab,8,q0_,aA0_) D4(Ab,12,q1_,aA1_) D4Q(bw0_,q0_,aB0_) D4Q(bw1_,q1_,aB1_) \
  D4Q(wq0_,q0_,aC0_) D4Q(wq1_,q1_,aC1_) \
  PH_TAIL() } while (0)

#define GATE(L, T) \
  if (tid < 128) { \
    const float2* gi2_ = (const float2*)pgf; \
    const float2* gh2_ = (const float2*)(pgf + 768); \
    float2 ar_ = gi2_[tid],      br_ = gh2_[tid]; \
    float2 az_ = gi2_[128+tid],  bz_ = gh2_[128+tid]; \
    float2 an_ = gi2_[256+tid],  bn_ = gh2_[256+tid]; \
    float r_ = sigmoidf((ar_.x + ar_.y) + (br_.x + br_.y) + bsum_r[L][tid]); \
    float z_ = sigmoidf((az_.x + az_.y) + (bz_.x + bz_.y) + bsum_z[L][tid]); \
    float n_ = tanh_f((an_.x + an_.y) + b_in[L][tid] + \
                      r_ * ((bn_.x + bn_.y) + b_hn[L][tid])); \
    float h_ = (1.f - z_) * n_ + z_ * h32[L][tid]; \
    h32[L][tid] = h_; f16 hh_ = (f16)h_; \
    srcbuf[(1 + (L)) * 128 + tid] = hh_; srcbuf[tid] = hh_; \
    if ((L) == 3) enc[(size_t)(T) * 128 + tid] = h_; \
  }

__global__ __attribute__((amdgpu_flat_work_group_size(512, 512)))
__attribute__((amdgpu_waves_per_eu(2, 2))) void gru_kernel(
    const f16* __restrict__ w16, const float* __restrict__ bih,
    const float* __restrict__ bhh, const float* __restrict__ zvec,
    float* __restrict__ enc) {
  const int tid = threadIdx.x;

  __shared__ __align__(16) float4 wldsB2[4096];       // 64 KB: B-rows layer 2
  __shared__ __align__(16) float4 wldsB3[4096];       // 64 KB: B-rows layer 3
  __shared__ __align__(16) float pgbuf[1536];         // 6 KB
  __shared__ __align__(16) f16 srcbuf[640];           // 1.25 KB
  __shared__ __align__(16) float h32[4][128];         // 2 KB
  __shared__ __align__(16) float cur32[128];          // 0.5 KB
  __shared__ float bsum_r[4][128], bsum_z[4][128];    // 4 KB
  __shared__ float b_in[4][128], b_hn[4][128];        // 4 KB

  float* const pgf = pgbuf;
  const f16* const srcf = srcbuf;

  // Row-grouped unit mapping.
  const int side = tid >> 8;           // 0 = gi (W_ih), 1 = gh (W_hh)
  const int ti = tid & 255;
  const int half = ti & 1;
  const int hs = half * 64;
  const int rb = 3 * (ti >> 1);        // rows rb, rb+1, rb+2 of [0,384)
  const int d0 = side * 768 + rb * 2 + half;
  const int soff_base = side ? (128 + hs) : hs;
  const int sideOff = side * 128;
  const int wAb_ = side * 196608 + rb * 128 + hs;  // A-row base, layer 0
  const int wCb = wAb_ + 256;                      // C-row base, layer 0

  // Register-resident weights: A-rows layers 0-3, B-rows layers 0-1.
  f32x16 rA0a, rA0b, rA1a, rA1b, rA2a, rA2b, rA3a, rA3b, rB0a, rB0b, rB1a, rB1b;
  LOAD_W16(rA0a, rA0b, w16 + wAb_);
  LOAD_W16(rA1a, rA1b, w16 + wAb_ + 49152);
  LOAD_W16(rA2a, rA2b, w16 + wAb_ + 2 * 49152);
  LOAD_W16(rA3a, rA3b, w16 + wAb_ + 3 * 49152);
  LOAD_W16(rB0a, rB0b, w16 + wAb_ + 128);
  LOAD_W16(rB1a, rB1b, w16 + wAb_ + 49152 + 128);
  // Anchor: opaque to remat/sinking; with the 256-VGPR budget (2 waves/EU)
  // the allocator keeps them resident instead of spilling.
  asm volatile("" : "+v"(rA0a), "+v"(rA0b), "+v"(rA1a), "+v"(rA1b),
                    "+v"(rA2a), "+v"(rA2b));
  asm volatile("" : "+v"(rA3a), "+v"(rA3b), "+v"(rB0a), "+v"(rB0b),
                    "+v"(rB1a), "+v"(rB1b));

  // LDS-resident weights: B-rows layers 2,3. Slot layout [chunk][tid] so a
  // wave's ds_read_b128 is lane-contiguous (conflict-free).
  {
    const float4* p2 = (const float4*)(w16 + wAb_ + 2 * 49152 + 128);
    const float4* p3 = (const float4*)(w16 + wAb_ + 3 * 49152 + 128);
    #pragma unroll
    for (int c = 0; c < 8; ++c) {
      wldsB2[c * 512 + tid] = p2[c];
      wldsB3[c * 512 + tid] = p3[c];
    }
  }

  if (tid < 128) {
    cur32[tid] = zvec[tid];
    srcbuf[tid] = (f16)0.f;
    #pragma unroll
    for (int l = 0; l < 4; ++l) {
      h32[l][tid] = 0.f;
      srcbuf[(1 + l) * 128 + tid] = (f16)0.f;
    }
  }
  {
    int l_ = tid >> 7, row_ = tid & 127;
    bsum_r[l_][row_] = bih[l_*384 + row_]       + bhh[l_*384 + row_];
    bsum_z[l_][row_] = bih[l_*384 + 128 + row_] + bhh[l_*384 + 128 + row_];
    b_in[l_][row_]   = bih[l_*384 + 256 + row_];
    b_hn[l_][row_]   = bhh[l_*384 + 256 + row_];
  }
  __syncthreads();

  // ---- peeled step t = 0: layer-0 gi in f32 (z ~1e7 overflows f16) ----
  {
    if (tid < 256) {  // side == 0: f32 path against resident regs + global C
      const float* xs_ = cur32 + hs;
      { float a0_ = 0.f, a1_ = 0.f;
        F32T16(rA0a, xs_, 0) F32T16(rA0b, xs_, 32)
        pgf[d0] = a0_ + a1_; }
      { float a0_ = 0.f, a1_ = 0.f;
        F32T16(rB0a, xs_, 0) F32T16(rB0b, xs_, 32)
        pgf[d0 + 2] = a0_ + a1_; }
      { float a0_ = 0.f, a1_ = 0.f;
        const f16x2* wp_ = (const f16x2*)(w16 + wCb);
        for (int k = 0; k < 32; ++k) {
          f16x2 w_ = wp_[k];
          a0_ += (float)w_[0] * xs_[2 * k];
          a1_ += (float)w_[1] * xs_[2 * k + 1];
        }
        pgf[d0 + 4] = a0_ + a1_; }
    } else {          // side == 1: h16 == 0 -> normal path yields zeros
      PH_R(0, rA0a, rA0b, rB0a, rB0b);
    }
    __syncthreads();
    GATE(0, 0)
    __syncthreads();
    PH_R(1, rA1a, rA1b, rB1a, rB1b);
    __syncthreads();
    GATE(1, 0)
    __syncthreads();
    PH_L(2, rA2a, rA2b, wldsB2);
    __syncthreads();
    GATE(2, 0)
    __syncthreads();
    PH_L(3, rA3a, rA3b, wldsB3);
    __syncthreads();
    GATE(3, 0)
    __syncthreads();
  }

  #pragma unroll 1
  for (int t = 1; t < NEVT; ++t) {
    PH_R(0, rA0a, rA0b, rB0a, rB0b);
    __syncthreads();
    GATE(0, t)
    __syncthreads();
    PH_R(1, rA1a, rA1b, rB1a, rB1b);
    __syncthreads();
    GATE(1, t)
    __syncthreads();
    PH_L(2, rA2a, rA2b, wldsB2);
    __syncthreads();
    GATE(2, t)
    __syncthreads();
    PH_L(3, rA3a, rA3b, wldsB3);
    __syncthreads();
    GATE(3, t)
    __syncthreads();
  }
}

// ---------------- Output heads ----------------
__global__ __launch_bounds__(128) void heads_kernel(
    const float* __restrict__ enc,
    const float* __restrict__ ah_w1, const float* __restrict__ ah_b1,
    const float* __restrict__ ah_w2, const float* __restrict__ ah_b2,
    const float* __restrict__ ah_w, const float* __restrict__ ah_b,
    const float* __restrict__ ph_w1, const float* __restrict__ ph_b1,
    const float* __restrict__ ph_w2, const float* __restrict__ ph_b2,
    const float* __restrict__ ph_w, const float* __restrict__ ph_b,
    const float* __restrict__ mh_w1, const float* __restrict__ mh_b1,
    const float* __restrict__ mh_w2, const float* __restrict__ mh_b2,
    const float* __restrict__ mh_w, const float* __restrict__ mh_b,
    float* __restrict__ oa, float* __restrict__ op, float* __restrict__ om) {
  const int u = threadIdx.x;
  const int r0 = blockIdx.x * 8;
  __shared__ float eb[8][128], xb[8][128], hb[8][128];
  #pragma unroll
  for (int r = 0; r < 8; ++r) eb[r][u] = enc[(size_t)(r0 + r) * 128 + u];
  // ---- atoms head ----
  #pragma unroll
  for (int r = 0; r < 8; ++r) xb[r][u] = eb[r][u];
  __syncthreads();
  for (int blk = 0; blk < 2; ++blk)
    res_block(xb, hb, ah_w1 + blk * 16384, ah_b1 + blk * 128,
              ah_w2 + blk * 16384, ah_b2 + blk * 128, u);
  {
    float acc[8];
    float bb = ah_b[u];
    #pragma unroll
    for (int r = 0; r < 8; ++r) acc[r] = bb;
    #pragma unroll 4
    for (int k = 0; k < 128; ++k) {
      float w = ah_w[u * 128 + k];
      #pragma unroll
      for (int r = 0; r < 8; ++r) acc[r] += w * xb[r][k];
    }
    #pragma unroll
    for (int r = 0; r < 8; ++r) oa[(size_t)(r0 + r) * 128 + u] = acc[r];
  }
  __syncthreads();
  // ---- pos head ----
  #pragma unroll
  for (int r = 0; r < 8; ++r) xb[r][u] = eb[r][u];
  __syncthreads();
  for (int blk = 0; blk < 2; ++blk)
    res_block(xb, hb, ph_w1 + blk * 16384, ph_b1 + blk * 128,
              ph_w2 + blk * 16384, ph_b2 + blk * 128, u);
  if (u < 8) {
    int r = u;
    float s = ph_b[0];
    for (int k = 0; k < 128; ++k) s += ph_w[k] * xb[r][k];
    s = s < 0.f ? 0.f : (s > 1.f ? 1.f : s);
    op[r0 + r] = s;
  }
  __syncthreads();
  // ---- mags head ----
  #pragma unroll
  for (int r = 0; r < 8; ++r) xb[r][u] = eb[r][u];
  __syncthreads();
  for (int blk = 0; blk < 2; ++blk)
    res_block(xb, hb, mh_w1 + blk * 16384, mh_b1 + blk * 128,
              mh_w2 + blk * 16384, mh_b2 + blk * 128, u);
  if (u < 8) {
    int r = u;
    float s = mh_b[0];
    for (int k = 0; k < 128; ++k) s += mh_w[k] * xb[r][k];
    om[r0 + r] = s;
  }
}

extern "C" void kernel_launch(void* const* d_in, const int* in_sizes, int n_in,
                              void* d_out, int out_size, void* d_ws, size_t ws_size,
                              hipStream_t stream) {
  const int* atom = (const int*)d_in[0];
  const float* tvec = (const float*)d_in[1];
  const float* mvec = (const float*)d_in[2];
  const float* atom_emb = (const float*)d_in[3];
  const float* mag_w = (const float*)d_in[4];
  const float* mag_b = (const float*)d_in[5];
  const float* pos_w = (const float*)d_in[6];
  const float* pos_b = (const float*)d_in[7];
  const float* reduce_w = (const float*)d_in[8];
  const float* reduce_b = (const float*)d_in[9];
  const float* net_w1 = (const float*)d_in[10];
  const float* net_b1 = (const float*)d_in[11];
  const float* net_w2 = (const float*)d_in[12];
  const float* net_b2 = (const float*)d_in[13];
  const float* final_w = (const float*)d_in[14];
  const float* final_b = (const float*)d_in[15];
  const float* redg_w = (const float*)d_in[16];
  const float* redg_b = (const float*)d_in[17];
  const float* wg_w1 = (const float*)d_in[18];
  const float* wg_b1 = (const float*)d_in[19];
  const float* wg_w2 = (const float*)d_in[20];
  const float* wg_b2 = (const float*)d_in[21];
  const float* gfinal_w = (const float*)d_in[22];
  const float* gfinal_b = (const float*)d_in[23];
  const float* gru_wih = (const float*)d_in[24];
  const float* gru_whh = (const float*)d_in[25];
  const float* gru_bih = (const float*)d_in[26];
  const float* gru_bhh = (const float*)d_in[27];
  const float* ah_w1 = (const float*)d_in[28];
  const float* ah_b1 = (const float*)d_in[29];
  const float* ah_w2 = (const float*)d_in[30];
  const float* ah_b2 = (const float*)d_in[31];
  const float* ah_w = (const float*)d_in[32];
  const float* ah_b = (const float*)d_in[33];
  const float* ph_w1 = (const float*)d_in[34];
  const float* ph_b1 = (const float*)d_in[35];
  const float* ph_w2 = (const float*)d_in[36];
  const float* ph_b2 = (const float*)d_in[37];
  const float* ph_w = (const float*)d_in[38];
  const float* ph_b = (const float*)d_in[39];
  const float* mh_w1 = (const float*)d_in[40];
  const float* mh_b1 = (const float*)d_in[41];
  const float* mh_w2 = (const float*)d_in[42];
  const float* mh_b2 = (const float*)d_in[43];
  const float* mh_w = (const float*)d_in[44];
  const float* mh_b = (const float*)d_in[45];

  float* out = (float*)d_out;
  float* oa = out;                        // atoms [N,128]
  float* op = out + (size_t)NEVT * 128;   // pos [N]
  float* om = op + NEVT;                  // mags [N]
  float* oz = om + NEVT;                  // z [128]

  float* enc = (float*)d_ws;              // encodings [N,128] : 16 MB
  float* pg = enc + (size_t)NEVT * 128;   // stage-1 partials: 2 MB (reused for w16)
  float* pz = pg + (size_t)NBLK * 128;    // stage-2 partials: 2 MB
  float* gv = pz + (size_t)NBLK * 128;    // g [128]
  float* xf = oa;  // stage-1 output staged in atoms region; heads overwrite later

  // f16 weight copies overlay the pg region once pg has been reduced into gv.
  f16* w16i = (f16*)pg;                   // 384 KB
  f16* w16h = w16i + 196608;              // 384 KB (contiguous with w16i)

  enc1_kernel<<<NBLK, 128, 0, stream>>>(atom, tvec, mvec, atom_emb, mag_w, mag_b,
      pos_w, pos_b, reduce_w, reduce_b, net_w1, net_b1, net_w2, net_b2,
      final_w, final_b, xf, pg);
  reduce_kernel<<<1, 1024, 0, stream>>>(pg, NBLK, gv);
  wprep_kernel<<<768, 256, 0, stream>>>(gru_wih, gru_whh, w16i, w16h);
  enc2_kernel<<<NBLK, 128, 0, stream>>>(xf, gv, redg_w, redg_b, wg_w1, wg_b1,
      wg_w2, wg_b2, gfinal_w, gfinal_b, pz);
  reduce_kernel<<<1, 1024, 0, stream>>>(pz, NBLK, oz);
  gru_kernel<<<1, 512, 0, stream>>>(w16i, gru_bih, gru_bhh, oz, enc);
  heads_kernel<<<NBLK, 128, 0, stream>>>(enc, ah_w1, ah_b1, ah_w2, ah_b2, ah_w, ah_b,
      ph_w1, ph_b1, ph_w2, ph_b2, ph_w, ph_b, mh_w1, mh_b1, mh_w2, mh_b2, mh_w, mh_b,
      oa, op, om);
}